// Round 1
// baseline (1946.437 us; speedup 1.0000x reference)
//
#include <hip/hip_runtime.h>

#define N_NODES 100000
#define N_EDGES 1200000

// broadcast lane k's value to all lanes via v_readlane (SGPR), no LDS traffic.
// k must be wave-uniform (compile-time after unroll, or uniform loop index).
__device__ __forceinline__ float rl_f(float v, int k) {
  return __int_as_float(__builtin_amdgcn_readlane(__float_as_int(v), k));
}
__device__ __forceinline__ int rl_i(int v, int k) {
  return __builtin_amdgcn_readlane(v, k);
}

// ---------------- CSR build ----------------

__global__ void hist_k(const int* __restrict__ ei, int* __restrict__ deg, int E) {
  int e = blockIdx.x * blockDim.x + threadIdx.x;
  if (e < E) atomicAdd(&deg[ei[E + e]], 1);
}

// single-block exclusive scan over N=100k (1024 threads, sequential 1024-chunks)
__global__ void scan_k(const int* __restrict__ deg, int* __restrict__ off,
                       int* __restrict__ pos, int n) {
  __shared__ int wpart[16];
  __shared__ int wpre[16];
  __shared__ int carry;
  int tid = threadIdx.x, lane = tid & 63, wid = tid >> 6;
  if (tid == 0) carry = 0;
  __syncthreads();
  for (int base = 0; base < n; base += 1024) {
    int i = base + tid;
    int v = (i < n) ? deg[i] : 0;
    int x = v;
    #pragma unroll
    for (int o = 1; o < 64; o <<= 1) {
      int y = __shfl_up(x, o);
      if (lane >= o) x += y;
    }
    if (lane == 63) wpart[wid] = x;
    __syncthreads();
    if (tid == 0) {
      int run = carry;
      #pragma unroll
      for (int w = 0; w < 16; w++) { int t = wpart[w]; wpre[w] = run; run += t; }
      carry = run;
    }
    __syncthreads();
    int excl = x - v + wpre[wid];
    if (i < n) { off[i] = excl; pos[i] = excl; }
    __syncthreads();
  }
  if (threadIdx.x == 0) off[n] = carry;
}

__global__ void fill_k(const int* __restrict__ ei, int* __restrict__ pos,
                       int* __restrict__ csr, int E) {
  int e = blockIdx.x * blockDim.x + threadIdx.x;
  if (e < E) {
    int d = ei[E + e];
    int p = atomicAdd(&pos[d], 1);
    csr[p] = ei[e];
  }
}

// ---------------- SAGE layer: aggregate + matvec + LN + relu (fused) ----------------
// wave per node, lane = feature. Weights staged in LDS (32KB -> 5 blocks/CU).

__global__ __launch_bounds__(256) void sage_k(
    const float* __restrict__ X, const int* __restrict__ off, const int* __restrict__ csr,
    const float* __restrict__ wl, const float* __restrict__ wr, const float* __restrict__ bias,
    const float* __restrict__ g, const float* __restrict__ lb,
    float* __restrict__ out, int n) {
  __shared__ float wls[4096];
  __shared__ float wrs[4096];
  for (int t = threadIdx.x; t < 4096; t += 256) { wls[t] = wl[t]; wrs[t] = wr[t]; }
  __syncthreads();
  int lane = threadIdx.x & 63;
  int wave = blockIdx.x * 4 + (threadIdx.x >> 6);
  int nw = gridDim.x * 4;
  for (int i = wave; i < n; i += nw) {
    int s0 = off[i], s1 = off[i + 1];
    float acc = 0.f;
    for (int base = s0; base < s1; base += 64) {
      int rem = s1 - base;
      int cnt = rem < 64 ? rem : 64;
      int s = (lane < cnt) ? csr[base + lane] : 0;
      int j = 0;
      for (; j + 4 <= cnt; j += 4) {   // 4-deep load ILP for the random row gathers
        int a0 = rl_i(s, j), a1 = rl_i(s, j + 1), a2 = rl_i(s, j + 2), a3 = rl_i(s, j + 3);
        float v0 = X[a0 * 64 + lane], v1 = X[a1 * 64 + lane];
        float v2 = X[a2 * 64 + lane], v3 = X[a3 * 64 + lane];
        acc += (v0 + v1) + (v2 + v3);
      }
      for (; j < cnt; j++) {
        int a = rl_i(s, j);
        acc += X[a * 64 + lane];
      }
    }
    int d = s1 - s0;
    float mean = acc / fmaxf((float)d, 1.f);
    float xi = X[i * 64 + lane];
    float o = bias[lane];
    #pragma unroll
    for (int k = 0; k < 64; k++) {
      o += rl_f(mean, k) * wls[k * 64 + lane] + rl_f(xi, k) * wrs[k * 64 + lane];
    }
    // LayerNorm over 64 features (one wave) + relu
    float sum = o;
    #pragma unroll
    for (int m = 1; m < 64; m <<= 1) sum += __shfl_xor(sum, m);
    float mu = sum * (1.f / 64.f);
    float dif = o - mu;
    float s2 = dif * dif;
    #pragma unroll
    for (int m = 1; m < 64; m <<= 1) s2 += __shfl_xor(s2, m);
    float var = s2 * (1.f / 64.f);
    float y = dif * rsqrtf(var + 1e-5f) * g[lane] + lb[lane];
    out[i * 64 + lane] = fmaxf(y, 0.f);
  }
}

// ---------------- per-node precompute: p = A*z, q = B*z + cb1 ----------------
// A = cw1 rows 0..63 (z_src block), B = cw1 rows 64..127 (z_dst block)

__global__ __launch_bounds__(256) void pq_k(
    const float* __restrict__ Z, const float* __restrict__ cw1, const float* __restrict__ cb1,
    float* __restrict__ P, float* __restrict__ Q, int n) {
  __shared__ float As[4096];
  __shared__ float Bs[4096];
  for (int t = threadIdx.x; t < 4096; t += 256) { As[t] = cw1[t]; Bs[t] = cw1[4096 + t]; }
  __syncthreads();
  int lane = threadIdx.x & 63;
  int wave = blockIdx.x * 4 + (threadIdx.x >> 6);
  int nw = gridDim.x * 4;
  for (int i = wave; i < n; i += nw) {
    float zv = Z[i * 64 + lane];
    float pa = 0.f, qa = cb1[lane];
    #pragma unroll
    for (int k = 0; k < 64; k++) {
      float m = rl_f(zv, k);
      pa += m * As[k * 64 + lane];
      qa += m * Bs[k * 64 + lane];
    }
    P[i * 64 + lane] = pa;
    Q[i * 64 + lane] = qa;
  }
}

// ---------------- edge classifier ----------------
// wave per edge; MLP weights register-resident per lane (col j of C/D/W2),
// activations broadcast via v_readlane. C = cw1 rows 128..191 (prod block),
// D = cw1 rows 192..223 (edge_attr block).

__global__ __launch_bounds__(256, 2) void edge_k(
    const int* __restrict__ ei, const float* __restrict__ ea,
    const float* __restrict__ Z, const float* __restrict__ P, const float* __restrict__ Q,
    const float* __restrict__ cw1, const float* __restrict__ cw2, const float* __restrict__ cb2,
    const float* __restrict__ cw3, const float* __restrict__ cb3,
    float* __restrict__ out, int E) {
  int lane = threadIdx.x & 63;
  int j32 = lane & 31;
  float wc[64], wd[32], w2[64];
  #pragma unroll
  for (int k = 0; k < 64; k++) wc[k] = cw1[(128 + k) * 64 + lane];
  #pragma unroll
  for (int k = 0; k < 32; k++) wd[k] = cw1[(192 + k) * 64 + lane];
  #pragma unroll
  for (int k = 0; k < 64; k++) w2[k] = cw2[k * 32 + j32];   // lanes 32..63 duplicate cols
  float w3v = cw3[j32];
  float cb2v = cb2[j32];
  float cb3v = cb3[0];
  int wave = blockIdx.x * 4 + (threadIdx.x >> 6);
  int nw = gridDim.x * 4;
  for (int e = wave; e < E; e += nw) {
    int s = ei[e], d = ei[E + e];
    float zs = Z[s * 64 + lane];
    float zd = Z[d * 64 + lane];
    float a0 = P[s * 64 + lane] + Q[d * 64 + lane];
    float eav = ea[e * 32 + j32];
    float pr = zs * zd;
    float a1 = 0.f, a2s = 0.f, a3 = 0.f;
    #pragma unroll
    for (int k = 0; k < 64; k += 4) {        // h1 += C^T * prod  (4-acc ILP)
      a0  += rl_f(pr, k)     * wc[k];
      a1  += rl_f(pr, k + 1) * wc[k + 1];
      a2s += rl_f(pr, k + 2) * wc[k + 2];
      a3  += rl_f(pr, k + 3) * wc[k + 3];
    }
    #pragma unroll
    for (int k = 0; k < 32; k += 4) {        // h1 += D^T * edge_attr
      a0  += rl_f(eav, k)     * wd[k];
      a1  += rl_f(eav, k + 1) * wd[k + 1];
      a2s += rl_f(eav, k + 2) * wd[k + 2];
      a3  += rl_f(eav, k + 3) * wd[k + 3];
    }
    float h1 = fmaxf((a0 + a1) + (a2s + a3), 0.f);
    float b0 = cb2v, b1 = 0.f, b2 = 0.f, b3 = 0.f;
    #pragma unroll
    for (int k = 0; k < 64; k += 4) {        // h2 = relu(W2^T h1 + cb2)
      b0 += rl_f(h1, k)     * w2[k];
      b1 += rl_f(h1, k + 1) * w2[k + 1];
      b2 += rl_f(h1, k + 2) * w2[k + 2];
      b3 += rl_f(h1, k + 3) * w2[k + 3];
    }
    float h2 = fmaxf((b0 + b1) + (b2 + b3), 0.f);
    float v = h2 * w3v;                       // logit; lanes 32..63 duplicate -> x2
    #pragma unroll
    for (int m = 1; m < 64; m <<= 1) v += __shfl_xor(v, m);
    if (lane == 0) out[e] = 0.5f * v + cb3v;
  }
}

// ---------------- launch ----------------

extern "C" void kernel_launch(void* const* d_in, const int* in_sizes, int n_in,
                              void* d_out, int out_size, void* d_ws, size_t ws_size,
                              hipStream_t stream) {
  const float* x   = (const float*)d_in[0];
  const int*   ei  = (const int*)d_in[1];
  const float* ea  = (const float*)d_in[2];
  const float* wl0 = (const float*)d_in[3];
  const float* wr0 = (const float*)d_in[4];
  const float* b0  = (const float*)d_in[5];
  const float* g0  = (const float*)d_in[6];
  const float* lb0 = (const float*)d_in[7];
  const float* wl1 = (const float*)d_in[8];
  const float* wr1 = (const float*)d_in[9];
  const float* b1  = (const float*)d_in[10];
  const float* g1  = (const float*)d_in[11];
  const float* lb1 = (const float*)d_in[12];
  const float* cw1 = (const float*)d_in[13];
  const float* cb1 = (const float*)d_in[14];
  const float* cw2 = (const float*)d_in[15];
  const float* cb2 = (const float*)d_in[16];
  const float* cw3 = (const float*)d_in[17];
  const float* cb3 = (const float*)d_in[18];
  float* out = (float*)d_out;
  const int N = N_NODES, E = N_EDGES;

  // workspace carve (ws re-poisoned 0xAA each call -> rebuild everything)
  char* wsb = (char*)d_ws;
  int* deg = (int*)wsb;                  // N
  int* off = deg + N;                    // N+1
  int* pos = off + N + 1;                // N
  int* csr = pos + N;                    // E
  float* h = (float*)(csr + E);          // N*64
  float* z = h + (size_t)N * 64;         // N*64
  float* q = z + (size_t)N * 64;         // N*64
  float* p = h;                          // alias: h is dead after layer 1

  hipMemsetAsync(deg, 0, N * sizeof(int), stream);
  hist_k<<<(E + 255) / 256, 256, 0, stream>>>(ei, deg, E);
  scan_k<<<1, 1024, 0, stream>>>(deg, off, pos, N);
  fill_k<<<(E + 255) / 256, 256, 0, stream>>>(ei, pos, csr, E);
  sage_k<<<1280, 256, 0, stream>>>(x, off, csr, wl0, wr0, b0, g0, lb0, h, N);
  sage_k<<<1280, 256, 0, stream>>>(h, off, csr, wl1, wr1, b1, g1, lb1, z, N);
  pq_k<<<1280, 256, 0, stream>>>(z, cw1, cb1, p, q, N);
  edge_k<<<1024, 256, 0, stream>>>(ei, ea, z, p, q, cw1, cw2, cb2, cw3, cb3, out, E);
}

// Round 2
// 855.423 us; speedup vs baseline: 2.2754x; 2.2754x over previous
//
#include <hip/hip_runtime.h>
#include <hip/hip_bf16.h>

#define N_NODES 100000
#define N_EDGES 1200000

typedef __attribute__((ext_vector_type(8))) short bfrag;
typedef __attribute__((ext_vector_type(4))) float ffrag;

union FragU { uint4 v; uint32_t u[4]; bfrag f; };

__device__ __forceinline__ float rl_f(float v, int k) {
  return __int_as_float(__builtin_amdgcn_readlane(__float_as_int(v), k));
}
__device__ __forceinline__ int rl_i(int v, int k) {
  return __builtin_amdgcn_readlane(v, k);
}
__device__ __forceinline__ ushort bfbits(float a) {
  union { __hip_bfloat16 h; ushort u; } c; c.h = __float2bfloat16(a); return c.u;
}
__device__ __forceinline__ uint32_t pkbf(float a, float b) {
  union { __hip_bfloat162 h; uint32_t u; } c;
  c.h = __float22bfloat162_rn(float2{a, b}); return c.u;
}
__device__ __forceinline__ uint32_t mul2bf(uint32_t a, uint32_t b) {
  union { uint32_t u; __hip_bfloat162 h; } x, y, r;
  x.u = a; y.u = b; r.h = __hmul2(x.h, y.h); return r.u;
}

// ---------------- CSR build ----------------

__global__ void hist_k(const int* __restrict__ ei, int* __restrict__ deg, int E) {
  int e = blockIdx.x * blockDim.x + threadIdx.x;
  if (e < E) atomicAdd(&deg[ei[E + e]], 1);
}

__global__ void scan_k(const int* __restrict__ deg, int* __restrict__ off,
                       int* __restrict__ pos, int n) {
  __shared__ int wpart[16];
  __shared__ int wpre[16];
  __shared__ int carry;
  int tid = threadIdx.x, lane = tid & 63, wid = tid >> 6;
  if (tid == 0) carry = 0;
  __syncthreads();
  for (int base = 0; base < n; base += 1024) {
    int i = base + tid;
    int v = (i < n) ? deg[i] : 0;
    int x = v;
    #pragma unroll
    for (int o = 1; o < 64; o <<= 1) {
      int y = __shfl_up(x, o);
      if (lane >= o) x += y;
    }
    if (lane == 63) wpart[wid] = x;
    __syncthreads();
    if (tid == 0) {
      int run = carry;
      #pragma unroll
      for (int w = 0; w < 16; w++) { int t = wpart[w]; wpre[w] = run; run += t; }
      carry = run;
    }
    __syncthreads();
    int excl = x - v + wpre[wid];
    if (i < n) { off[i] = excl; pos[i] = excl; }
    __syncthreads();
  }
  if (threadIdx.x == 0) off[n] = carry;
}

__global__ void fill_k(const int* __restrict__ ei, int* __restrict__ pos,
                       int* __restrict__ csr, int E) {
  int e = blockIdx.x * blockDim.x + threadIdx.x;
  if (e < E) {
    int d = ei[E + e];
    int p = atomicAdd(&pos[d], 1);
    csr[p] = ei[e];
  }
}

// ---------------- SAGE layer (aggregate + matvec + LN + relu) ----------------

template <bool BF16OUT>
__global__ __launch_bounds__(256) void sage_k(
    const float* __restrict__ X, const int* __restrict__ off, const int* __restrict__ csr,
    const float* __restrict__ wl, const float* __restrict__ wr, const float* __restrict__ bias,
    const float* __restrict__ g, const float* __restrict__ lb,
    void* __restrict__ outv, int n) {
  __shared__ float wls[4096];
  __shared__ float wrs[4096];
  for (int t = threadIdx.x; t < 4096; t += 256) { wls[t] = wl[t]; wrs[t] = wr[t]; }
  __syncthreads();
  int lane = threadIdx.x & 63;
  int wave = blockIdx.x * 4 + (threadIdx.x >> 6);
  int nw = gridDim.x * 4;
  for (int i = wave; i < n; i += nw) {
    int s0 = off[i], s1 = off[i + 1];
    float acc = 0.f;
    for (int base = s0; base < s1; base += 64) {
      int rem = s1 - base;
      int cnt = rem < 64 ? rem : 64;
      int s = (lane < cnt) ? csr[base + lane] : 0;
      int j = 0;
      for (; j + 4 <= cnt; j += 4) {
        int a0 = rl_i(s, j), a1 = rl_i(s, j + 1), a2 = rl_i(s, j + 2), a3 = rl_i(s, j + 3);
        float v0 = X[a0 * 64 + lane], v1 = X[a1 * 64 + lane];
        float v2 = X[a2 * 64 + lane], v3 = X[a3 * 64 + lane];
        acc += (v0 + v1) + (v2 + v3);
      }
      for (; j < cnt; j++) {
        int a = rl_i(s, j);
        acc += X[a * 64 + lane];
      }
    }
    int d = s1 - s0;
    float mean = acc / fmaxf((float)d, 1.f);
    float xi = X[i * 64 + lane];
    float o = bias[lane];
    #pragma unroll
    for (int k = 0; k < 64; k++) {
      o += rl_f(mean, k) * wls[k * 64 + lane] + rl_f(xi, k) * wrs[k * 64 + lane];
    }
    float sum = o;
    #pragma unroll
    for (int m = 1; m < 64; m <<= 1) sum += __shfl_xor(sum, m);
    float mu = sum * (1.f / 64.f);
    float dif = o - mu;
    float s2 = dif * dif;
    #pragma unroll
    for (int m = 1; m < 64; m <<= 1) s2 += __shfl_xor(s2, m);
    float var = s2 * (1.f / 64.f);
    float y = fmaxf(dif * rsqrtf(var + 1e-5f) * g[lane] + lb[lane], 0.f);
    if constexpr (BF16OUT) ((ushort*)outv)[i * 64 + lane] = bfbits(y);
    else ((float*)outv)[i * 64 + lane] = y;
  }
}

// ---------------- edge classifier: bf16 MFMA ----------------
// Per wave: 16 edges. Layer1: A=[16 x 224] = [zs|zd|zs*zd|ea] (regs, gathered),
// B=W1^T in swizzled LDS, 4 N-tiles x 7 K-steps of mfma_f32_16x16x32_bf16.
// h1 -> per-wave swizzled LDS tile (C-layout -> A-layout transpose).
// Layer2: K=64 (2 steps) x 2 N-tiles, W2^T in registers. Layer3: shuffle-reduce dot.

__global__ __launch_bounds__(256) void edge_mfma_k(
    const int* __restrict__ ei, const float* __restrict__ ea,
    const ushort* __restrict__ zb,
    const float* __restrict__ cw1, const float* __restrict__ cb1,
    const float* __restrict__ cw2, const float* __restrict__ cb2,
    const float* __restrict__ cw3, const float* __restrict__ cb3,
    float* __restrict__ out, int E) {
  __shared__ ushort wt1[64 * 256];      // W1^T [n][k], XOR-swizzled 16B blocks, 32KB
  __shared__ ushort h1b[4][16 * 64];    // per-wave h1 tile [m][n], swizzled, 2KB each
  const int tid = threadIdx.x;

  // stage W1^T: cw1 is [224][64] (k-major)
  for (int i = tid; i < 224 * 64; i += 256) {
    int k = i >> 6, n = i & 63;
    int blk = k >> 3;
    wt1[n * 256 + ((blk ^ (n & 7)) * 8) + (k & 7)] = bfbits(cw1[i]);
  }
  __syncthreads();

  const int lane = tid & 63, wid = tid >> 6;
  const int ln = lane & 15, q = lane >> 4;

  // per-lane constants
  float cb1v[4];
  #pragma unroll
  for (int t = 0; t < 4; t++) cb1v[t] = cb1[t * 16 + ln];
  float cb2a = cb2[ln], cb2b = cb2[16 + ln];
  float w3a = cw3[ln], w3b = cw3[16 + ln];
  float cb3v = cb3[0];

  // W2^T fragments in registers: B2[t2][kk2], k = kk2*32 + q*8 + j, n = t2*16 + ln
  FragU w2f[2][2];
  #pragma unroll
  for (int t2 = 0; t2 < 2; t2++) {
    #pragma unroll
    for (int kk = 0; kk < 2; kk++) {
      #pragma unroll
      for (int p = 0; p < 4; p++) {
        int k = kk * 32 + q * 8 + p * 2;
        int n = t2 * 16 + ln;
        w2f[t2][kk].u[p] = pkbf(cw2[k * 32 + n], cw2[(k + 1) * 32 + n]);
      }
    }
  }

  ushort* hb = h1b[wid];
  const int ntiles = E >> 4;
  for (int t = blockIdx.x * 4 + wid; t < ntiles; t += gridDim.x * 4) {
    int e = t * 16 + ln;
    int s = ei[e], d = ei[E + e];

    FragU afr[7];
    #pragma unroll
    for (int kk = 0; kk < 2; kk++) {
      afr[kk].v     = ((const uint4*)zb)[(size_t)s * 8 + kk * 4 + q];   // zs
      afr[2 + kk].v = ((const uint4*)zb)[(size_t)d * 8 + kk * 4 + q];   // zd
    }
    #pragma unroll
    for (int kk = 0; kk < 2; kk++) {
      #pragma unroll
      for (int p = 0; p < 4; p++)
        afr[4 + kk].u[p] = mul2bf(afr[kk].u[p], afr[2 + kk].u[p]);      // prod
    }
    {
      float4 lo = ((const float4*)ea)[(size_t)e * 8 + q * 2];
      float4 hi = ((const float4*)ea)[(size_t)e * 8 + q * 2 + 1];
      afr[6].u[0] = pkbf(lo.x, lo.y); afr[6].u[1] = pkbf(lo.z, lo.w);
      afr[6].u[2] = pkbf(hi.x, hi.y); afr[6].u[3] = pkbf(hi.z, hi.w);
    }

    ffrag acc1[4];
    #pragma unroll
    for (int tt = 0; tt < 4; tt++) acc1[tt] = ffrag{0.f, 0.f, 0.f, 0.f};

    #pragma unroll
    for (int kk = 0; kk < 7; kk++) {
      bfrag a = afr[kk].f;
      #pragma unroll
      for (int tt = 0; tt < 4; tt++) {
        int n = tt * 16 + ln;
        int b = kk * 4 + q;
        const bfrag* bp = (const bfrag*)&wt1[n * 256 + ((b ^ (n & 7)) * 8)];
        acc1[tt] = __builtin_amdgcn_mfma_f32_16x16x32_bf16(a, *bp, acc1[tt], 0, 0, 0);
      }
    }

    // h1 = relu(acc1 + cb1) -> swizzled LDS (C-layout -> A-layout)
    #pragma unroll
    for (int tt = 0; tt < 4; tt++) {
      #pragma unroll
      for (int r = 0; r < 4; r++) {
        int m = q * 4 + r;
        int col = tt * 16 + ln;
        float v = fmaxf(acc1[tt][r] + cb1v[tt], 0.f);
        hb[m * 64 + (((col >> 3) ^ (m & 7)) * 8) + (col & 7)] = bfbits(v);
      }
    }

    ffrag acc2[2];
    acc2[0] = ffrag{0.f, 0.f, 0.f, 0.f};
    acc2[1] = ffrag{0.f, 0.f, 0.f, 0.f};
    #pragma unroll
    for (int kk = 0; kk < 2; kk++) {
      int b = kk * 4 + q;
      const bfrag* ap = (const bfrag*)&hb[ln * 64 + ((b ^ (ln & 7)) * 8)];
      bfrag a2 = *ap;
      acc2[0] = __builtin_amdgcn_mfma_f32_16x16x32_bf16(a2, w2f[0][kk].f, acc2[0], 0, 0, 0);
      acc2[1] = __builtin_amdgcn_mfma_f32_16x16x32_bf16(a2, w2f[1][kk].f, acc2[1], 0, 0, 0);
    }

    // layer3: logit[m] = sum_n relu(h2[m][n]) * w3[n] + cb3
    float p0, p1, p2, p3;
    {
      p0 = fmaxf(acc2[0][0] + cb2a, 0.f) * w3a + fmaxf(acc2[1][0] + cb2b, 0.f) * w3b;
      p1 = fmaxf(acc2[0][1] + cb2a, 0.f) * w3a + fmaxf(acc2[1][1] + cb2b, 0.f) * w3b;
      p2 = fmaxf(acc2[0][2] + cb2a, 0.f) * w3a + fmaxf(acc2[1][2] + cb2b, 0.f) * w3b;
      p3 = fmaxf(acc2[0][3] + cb2a, 0.f) * w3a + fmaxf(acc2[1][3] + cb2b, 0.f) * w3b;
    }
    #pragma unroll
    for (int o = 1; o < 16; o <<= 1) {
      p0 += __shfl_xor(p0, o);
      p1 += __shfl_xor(p1, o);
      p2 += __shfl_xor(p2, o);
      p3 += __shfl_xor(p3, o);
    }
    float keep = (ln == 0) ? p0 : (ln == 1) ? p1 : (ln == 2) ? p2 : p3;
    if (ln < 4) out[t * 16 + q * 4 + ln] = keep + cb3v;
  }
}

// ---------------- launch ----------------

extern "C" void kernel_launch(void* const* d_in, const int* in_sizes, int n_in,
                              void* d_out, int out_size, void* d_ws, size_t ws_size,
                              hipStream_t stream) {
  const float* x   = (const float*)d_in[0];
  const int*   ei  = (const int*)d_in[1];
  const float* ea  = (const float*)d_in[2];
  const float* wl0 = (const float*)d_in[3];
  const float* wr0 = (const float*)d_in[4];
  const float* b0  = (const float*)d_in[5];
  const float* g0  = (const float*)d_in[6];
  const float* lb0 = (const float*)d_in[7];
  const float* wl1 = (const float*)d_in[8];
  const float* wr1 = (const float*)d_in[9];
  const float* b1  = (const float*)d_in[10];
  const float* g1  = (const float*)d_in[11];
  const float* lb1 = (const float*)d_in[12];
  const float* cw1 = (const float*)d_in[13];
  const float* cb1 = (const float*)d_in[14];
  const float* cw2 = (const float*)d_in[15];
  const float* cb2 = (const float*)d_in[16];
  const float* cw3 = (const float*)d_in[17];
  const float* cb3 = (const float*)d_in[18];
  float* out = (float*)d_out;
  const int N = N_NODES, E = N_EDGES;

  uintptr_t pp = (uintptr_t)d_ws;
  auto alloc = [&](size_t bytes) {
    uintptr_t r = (pp + 63) & ~(uintptr_t)63; pp = r + bytes; return (void*)r;
  };
  int* deg = (int*)alloc((size_t)N * 4);
  int* off = (int*)alloc((size_t)(N + 1) * 4);
  int* pos = (int*)alloc((size_t)N * 4);
  int* csr = (int*)alloc((size_t)E * 4);
  float* h = (float*)alloc((size_t)N * 64 * 4);
  ushort* zbuf = (ushort*)alloc((size_t)N * 64 * 2);

  hipMemsetAsync(deg, 0, (size_t)N * 4, stream);
  hist_k<<<(E + 255) / 256, 256, 0, stream>>>(ei, deg, E);
  scan_k<<<1, 1024, 0, stream>>>(deg, off, pos, N);
  fill_k<<<(E + 255) / 256, 256, 0, stream>>>(ei, pos, csr, E);
  sage_k<false><<<1280, 256, 0, stream>>>(x, off, csr, wl0, wr0, b0, g0, lb0, h, N);
  sage_k<true><<<1280, 256, 0, stream>>>(h, off, csr, wl1, wr1, b1, g1, lb1, zbuf, N);
  edge_mfma_k<<<1024, 256, 0, stream>>>(ei, ea, zbuf, cw1, cb1, cw2, cb2, cw3, cb3, out, E);
}

// Round 3
// 584.654 us; speedup vs baseline: 3.3292x; 1.4631x over previous
//
#include <hip/hip_runtime.h>
#include <hip/hip_bf16.h>

#define N_NODES 100000
#define N_EDGES 1200000

typedef __attribute__((ext_vector_type(8))) short bfrag;
typedef __attribute__((ext_vector_type(4))) float ffrag;

union FragU { uint4 v; uint32_t u[4]; bfrag f; };

__device__ __forceinline__ float rl_f(float v, int k) {
  return __int_as_float(__builtin_amdgcn_readlane(__float_as_int(v), k));
}
__device__ __forceinline__ int rl_i(int v, int k) {
  return __builtin_amdgcn_readlane(v, k);
}
__device__ __forceinline__ ushort bfbits(float a) {
  union { __hip_bfloat16 h; ushort u; } c; c.h = __float2bfloat16(a); return c.u;
}
__device__ __forceinline__ uint32_t pkbf(float a, float b) {
  union { __hip_bfloat162 h; uint32_t u; } c;
  c.h = __float22bfloat162_rn(float2{a, b}); return c.u;
}
__device__ __forceinline__ uint32_t mul2bf(uint32_t a, uint32_t b) {
  union { uint32_t u; __hip_bfloat162 h; } x, y, r;
  x.u = a; y.u = b; r.h = __hmul2(x.h, y.h); return r.u;
}
__device__ __forceinline__ float bflo(uint32_t u) { return __int_as_float(u << 16); }
__device__ __forceinline__ float bfhi(uint32_t u) { return __int_as_float(u & 0xffff0000u); }

// ---------------- x -> bf16 ----------------

__global__ void cvt_k(const float* __restrict__ x, ushort* __restrict__ xb, int n2) {
  int i = blockIdx.x * blockDim.x + threadIdx.x;   // n2 = N*32 (pairs)
  if (i < n2) {
    float2 v = ((const float2*)x)[i];
    ((uint32_t*)xb)[i] = pkbf(v.x, v.y);
  }
}

// ---------------- CSR build ----------------

__global__ void hist_k(const int* __restrict__ ei, int* __restrict__ deg, int E) {
  int e = blockIdx.x * blockDim.x + threadIdx.x;
  if (e < E) atomicAdd(&deg[ei[E + e]], 1);
}

// 3-phase scan: per-block local scan, block-sum scan, add-back
__global__ __launch_bounds__(1024) void scan1_k(const int* __restrict__ deg,
                                                int* __restrict__ off,
                                                int* __restrict__ bsum, int n) {
  __shared__ int wpart[16];
  __shared__ int wpre[16];
  int tid = threadIdx.x, lane = tid & 63, wid = tid >> 6;
  int i = blockIdx.x * 1024 + tid;
  int v = (i < n) ? deg[i] : 0;
  int x = v;
  #pragma unroll
  for (int o = 1; o < 64; o <<= 1) {
    int y = __shfl_up(x, o);
    if (lane >= o) x += y;
  }
  if (lane == 63) wpart[wid] = x;
  __syncthreads();
  if (tid == 0) {
    int run = 0;
    #pragma unroll
    for (int w = 0; w < 16; w++) { int t = wpart[w]; wpre[w] = run; run += t; }
    bsum[blockIdx.x] = run;
  }
  __syncthreads();
  if (i < n) off[i] = x - v + wpre[wid];
}

__global__ void scan2_k(const int* __restrict__ bsum, int* __restrict__ bpre,
                        int* __restrict__ off, int nb, int n) {
  if (threadIdx.x == 0) {
    int run = 0;
    for (int b = 0; b < nb; b++) { int t = bsum[b]; bpre[b] = run; run += t; }
    off[n] = run;
  }
}

__global__ __launch_bounds__(1024) void scan3_k(int* __restrict__ off, int* __restrict__ pos,
                                                const int* __restrict__ bpre, int n) {
  int i = blockIdx.x * 1024 + threadIdx.x;
  if (i < n) {
    int o = off[i] + bpre[blockIdx.x];
    off[i] = o;
    pos[i] = o;
  }
}

__global__ void fill_k(const int* __restrict__ ei, int* __restrict__ pos,
                       int* __restrict__ csr, int E) {
  int e = blockIdx.x * blockDim.x + threadIdx.x;
  if (e < E) {
    int d = ei[E + e];
    int p = atomicAdd(&pos[d], 1);
    csr[p] = ei[e];
  }
}

// ---------------- mean aggregation (bf16 rows, 2 edges per load) ----------------
// wave per node; lanes 0-31 = even edges, 32-63 = odd edges; lane holds feature
// pair (2*f2, 2*f2+1). fp32 accumulation, bf16 output row.

__global__ __launch_bounds__(256) void agg_k(
    const ushort* __restrict__ Xb, const int* __restrict__ off, const int* __restrict__ csr,
    ushort* __restrict__ aggout, int n) {
  int lane = threadIdx.x & 63;
  int half = lane >> 5, f2 = lane & 31;
  int wave = blockIdx.x * 4 + (threadIdx.x >> 6);
  int nw = gridDim.x * 4;
  for (int i = wave; i < n; i += nw) {
    int s0 = off[i], s1 = off[i + 1];
    float a0 = 0.f, a1 = 0.f;
    for (int base = s0; base < s1; base += 64) {
      int rem = s1 - base;
      int cnt = rem < 64 ? rem : 64;
      int myidx = (lane < cnt) ? csr[base + lane] : 0;
      int j = 0;
      for (; j + 8 <= cnt; j += 8) {           // 4 loads in flight
        uint32_t us[4];
        #pragma unroll
        for (int p = 0; p < 4; p++) {
          int i0 = rl_i(myidx, j + 2 * p), i1 = rl_i(myidx, j + 2 * p + 1);
          int sel = half ? i1 : i0;
          us[p] = ((const uint32_t*)Xb)[(size_t)sel * 32 + f2];
        }
        #pragma unroll
        for (int p = 0; p < 4; p++) { a0 += bflo(us[p]); a1 += bfhi(us[p]); }
      }
      for (; j + 2 <= cnt; j += 2) {
        int i0 = rl_i(myidx, j), i1 = rl_i(myidx, j + 1);
        int sel = half ? i1 : i0;
        uint32_t u = ((const uint32_t*)Xb)[(size_t)sel * 32 + f2];
        a0 += bflo(u); a1 += bfhi(u);
      }
      if (j < cnt) {                            // odd tail edge: half 0 only
        int i0 = rl_i(myidx, j);
        uint32_t u = ((const uint32_t*)Xb)[(size_t)i0 * 32 + f2];
        if (half == 0) { a0 += bflo(u); a1 += bfhi(u); }
      }
    }
    a0 += __shfl_xor(a0, 32);
    a1 += __shfl_xor(a1, 32);
    int d = s1 - s0;
    float rdeg = 1.f / fmaxf((float)d, 1.f);
    if (half == 0)
      ((uint32_t*)aggout)[(size_t)i * 32 + f2] = pkbf(a0 * rdeg, a1 * rdeg);
  }
}

// ---------------- node linear + LN + relu via MFMA ----------------
// 16 nodes per wave. A = [mean | self] (K=128, bf16 rows), B = [wl;wr]^T in
// swizzled LDS. 4 k-steps x 4 n-tiles of mfma_f32_16x16x32_bf16, then LN over
// the 16-lane feature groups, bf16 output.

__global__ __launch_bounds__(256) void node_k(
    const ushort* __restrict__ agg, const ushort* __restrict__ selfb,
    const float* __restrict__ wl, const float* __restrict__ wr,
    const float* __restrict__ bias, const float* __restrict__ g, const float* __restrict__ lb,
    ushort* __restrict__ outb, int n) {
  __shared__ ushort wt[64 * 128];   // [n][k] swizzled, 16KB
  const int tid = threadIdx.x;
  for (int i = tid; i < 8192; i += 256) {
    int k = i >> 6, nn = i & 63;
    float v = (k < 64) ? wl[k * 64 + nn] : wr[(k - 64) * 64 + nn];
    wt[nn * 128 + (((k >> 3) ^ (nn & 7)) * 8) + (k & 7)] = bfbits(v);
  }
  __syncthreads();
  const int lane = tid & 63, wid = tid >> 6;
  const int ln = lane & 15, q = lane >> 4;
  float bias_n[4], g_n[4], lb_n[4];
  #pragma unroll
  for (int nt = 0; nt < 4; nt++) {
    bias_n[nt] = bias[nt * 16 + ln];
    g_n[nt] = g[nt * 16 + ln];
    lb_n[nt] = lb[nt * 16 + ln];
  }
  const int ntiles = (n + 15) >> 4;
  for (int t = blockIdx.x * 4 + wid; t < ntiles; t += gridDim.x * 4) {
    int node = t * 16 + ln;
    int nc = node < n ? node : n - 1;
    FragU afr[4];
    #pragma unroll
    for (int kk = 0; kk < 2; kk++) {
      afr[kk].v     = ((const uint4*)agg)[(size_t)nc * 8 + kk * 4 + q];
      afr[2 + kk].v = ((const uint4*)selfb)[(size_t)nc * 8 + kk * 4 + q];
    }
    ffrag acc[4];
    #pragma unroll
    for (int nt = 0; nt < 4; nt++) acc[nt] = ffrag{0.f, 0.f, 0.f, 0.f};
    #pragma unroll
    for (int kk = 0; kk < 4; kk++) {
      bfrag a = afr[kk].f;
      #pragma unroll
      for (int nt = 0; nt < 4; nt++) {
        int nn = nt * 16 + ln;
        int b = kk * 4 + q;
        const bfrag* bp = (const bfrag*)&wt[nn * 128 + ((b ^ (nn & 7)) * 8)];
        acc[nt] = __builtin_amdgcn_mfma_f32_16x16x32_bf16(a, *bp, acc[nt], 0, 0, 0);
      }
    }
    // epilogue: per accumulator row r, node m = t*16 + q*4 + r
    #pragma unroll
    for (int r = 0; r < 4; r++) {
      int m = t * 16 + q * 4 + r;
      float o[4];
      #pragma unroll
      for (int nt = 0; nt < 4; nt++) o[nt] = acc[nt][r] + bias_n[nt];
      float s = (o[0] + o[1]) + (o[2] + o[3]);
      #pragma unroll
      for (int mm = 1; mm < 16; mm <<= 1) s += __shfl_xor(s, mm);
      float mu = s * (1.f / 64.f);
      float v2 = 0.f;
      #pragma unroll
      for (int nt = 0; nt < 4; nt++) { float d2 = o[nt] - mu; v2 += d2 * d2; }
      #pragma unroll
      for (int mm = 1; mm < 16; mm <<= 1) v2 += __shfl_xor(v2, mm);
      float rs = rsqrtf(v2 * (1.f / 64.f) + 1e-5f);
      if (m < n) {
        #pragma unroll
        for (int nt = 0; nt < 4; nt++) {
          float y = fmaxf((o[nt] - mu) * rs * g_n[nt] + lb_n[nt], 0.f);
          outb[(size_t)m * 64 + nt * 16 + ln] = bfbits(y);
        }
      }
    }
  }
}

// ---------------- edge classifier: bf16 MFMA ----------------

__global__ __launch_bounds__(256) void edge_mfma_k(
    const int* __restrict__ ei, const float* __restrict__ ea,
    const ushort* __restrict__ zb,
    const float* __restrict__ cw1, const float* __restrict__ cb1,
    const float* __restrict__ cw2, const float* __restrict__ cb2,
    const float* __restrict__ cw3, const float* __restrict__ cb3,
    float* __restrict__ out, int E) {
  __shared__ ushort wt1[64 * 256];      // W1^T [n][k], XOR-swizzled, 32KB
  __shared__ ushort h1b[4][16 * 64];    // per-wave h1 tile, swizzled, 2KB each
  const int tid = threadIdx.x;

  for (int i = tid; i < 224 * 64; i += 256) {
    int k = i >> 6, n = i & 63;
    int blk = k >> 3;
    wt1[n * 256 + ((blk ^ (n & 7)) * 8) + (k & 7)] = bfbits(cw1[i]);
  }
  __syncthreads();

  const int lane = tid & 63, wid = tid >> 6;
  const int ln = lane & 15, q = lane >> 4;

  float cb1v[4];
  #pragma unroll
  for (int t = 0; t < 4; t++) cb1v[t] = cb1[t * 16 + ln];
  float cb2a = cb2[ln], cb2b = cb2[16 + ln];
  float w3a = cw3[ln], w3b = cw3[16 + ln];
  float cb3v = cb3[0];

  FragU w2f[2][2];
  #pragma unroll
  for (int t2 = 0; t2 < 2; t2++) {
    #pragma unroll
    for (int kk = 0; kk < 2; kk++) {
      #pragma unroll
      for (int p = 0; p < 4; p++) {
        int k = kk * 32 + q * 8 + p * 2;
        int n = t2 * 16 + ln;
        w2f[t2][kk].u[p] = pkbf(cw2[k * 32 + n], cw2[(k + 1) * 32 + n]);
      }
    }
  }

  ushort* hb = h1b[wid];
  const int ntiles = E >> 4;
  for (int t = blockIdx.x * 4 + wid; t < ntiles; t += gridDim.x * 4) {
    int e = t * 16 + ln;
    int s = ei[e], d = ei[E + e];

    FragU afr[7];
    #pragma unroll
    for (int kk = 0; kk < 2; kk++) {
      afr[kk].v     = ((const uint4*)zb)[(size_t)s * 8 + kk * 4 + q];
      afr[2 + kk].v = ((const uint4*)zb)[(size_t)d * 8 + kk * 4 + q];
    }
    #pragma unroll
    for (int kk = 0; kk < 2; kk++) {
      #pragma unroll
      for (int p = 0; p < 4; p++)
        afr[4 + kk].u[p] = mul2bf(afr[kk].u[p], afr[2 + kk].u[p]);
    }
    {
      float4 lo = ((const float4*)ea)[(size_t)e * 8 + q * 2];
      float4 hi = ((const float4*)ea)[(size_t)e * 8 + q * 2 + 1];
      afr[6].u[0] = pkbf(lo.x, lo.y); afr[6].u[1] = pkbf(lo.z, lo.w);
      afr[6].u[2] = pkbf(hi.x, hi.y); afr[6].u[3] = pkbf(hi.z, hi.w);
    }

    ffrag acc1[4];
    #pragma unroll
    for (int tt = 0; tt < 4; tt++) acc1[tt] = ffrag{0.f, 0.f, 0.f, 0.f};

    #pragma unroll
    for (int kk = 0; kk < 7; kk++) {
      bfrag a = afr[kk].f;
      #pragma unroll
      for (int tt = 0; tt < 4; tt++) {
        int n = tt * 16 + ln;
        int b = kk * 4 + q;
        const bfrag* bp = (const bfrag*)&wt1[n * 256 + ((b ^ (n & 7)) * 8)];
        acc1[tt] = __builtin_amdgcn_mfma_f32_16x16x32_bf16(a, *bp, acc1[tt], 0, 0, 0);
      }
    }

    #pragma unroll
    for (int tt = 0; tt < 4; tt++) {
      #pragma unroll
      for (int r = 0; r < 4; r++) {
        int m = q * 4 + r;
        int col = tt * 16 + ln;
        float v = fmaxf(acc1[tt][r] + cb1v[tt], 0.f);
        hb[m * 64 + (((col >> 3) ^ (m & 7)) * 8) + (col & 7)] = bfbits(v);
      }
    }

    ffrag acc2[2];
    acc2[0] = ffrag{0.f, 0.f, 0.f, 0.f};
    acc2[1] = ffrag{0.f, 0.f, 0.f, 0.f};
    #pragma unroll
    for (int kk = 0; kk < 2; kk++) {
      int b = kk * 4 + q;
      const bfrag* ap = (const bfrag*)&hb[ln * 64 + ((b ^ (ln & 7)) * 8)];
      bfrag a2 = *ap;
      acc2[0] = __builtin_amdgcn_mfma_f32_16x16x32_bf16(a2, w2f[0][kk].f, acc2[0], 0, 0, 0);
      acc2[1] = __builtin_amdgcn_mfma_f32_16x16x32_bf16(a2, w2f[1][kk].f, acc2[1], 0, 0, 0);
    }

    float p0, p1, p2, p3;
    {
      p0 = fmaxf(acc2[0][0] + cb2a, 0.f) * w3a + fmaxf(acc2[1][0] + cb2b, 0.f) * w3b;
      p1 = fmaxf(acc2[0][1] + cb2a, 0.f) * w3a + fmaxf(acc2[1][1] + cb2b, 0.f) * w3b;
      p2 = fmaxf(acc2[0][2] + cb2a, 0.f) * w3a + fmaxf(acc2[1][2] + cb2b, 0.f) * w3b;
      p3 = fmaxf(acc2[0][3] + cb2a, 0.f) * w3a + fmaxf(acc2[1][3] + cb2b, 0.f) * w3b;
    }
    #pragma unroll
    for (int o = 1; o < 16; o <<= 1) {
      p0 += __shfl_xor(p0, o);
      p1 += __shfl_xor(p1, o);
      p2 += __shfl_xor(p2, o);
      p3 += __shfl_xor(p3, o);
    }
    float keep = (ln == 0) ? p0 : (ln == 1) ? p1 : (ln == 2) ? p2 : p3;
    if (ln < 4) out[t * 16 + q * 4 + ln] = keep + cb3v;
  }
}

// ---------------- launch ----------------

extern "C" void kernel_launch(void* const* d_in, const int* in_sizes, int n_in,
                              void* d_out, int out_size, void* d_ws, size_t ws_size,
                              hipStream_t stream) {
  const float* x   = (const float*)d_in[0];
  const int*   ei  = (const int*)d_in[1];
  const float* ea  = (const float*)d_in[2];
  const float* wl0 = (const float*)d_in[3];
  const float* wr0 = (const float*)d_in[4];
  const float* b0  = (const float*)d_in[5];
  const float* g0  = (const float*)d_in[6];
  const float* lb0 = (const float*)d_in[7];
  const float* wl1 = (const float*)d_in[8];
  const float* wr1 = (const float*)d_in[9];
  const float* b1  = (const float*)d_in[10];
  const float* g1  = (const float*)d_in[11];
  const float* lb1 = (const float*)d_in[12];
  const float* cw1 = (const float*)d_in[13];
  const float* cb1 = (const float*)d_in[14];
  const float* cw2 = (const float*)d_in[15];
  const float* cb2 = (const float*)d_in[16];
  const float* cw3 = (const float*)d_in[17];
  const float* cb3 = (const float*)d_in[18];
  float* out = (float*)d_out;
  const int N = N_NODES, E = N_EDGES;
  const int NB = (N + 1023) / 1024;

  uintptr_t pp = (uintptr_t)d_ws;
  auto alloc = [&](size_t bytes) {
    uintptr_t r = (pp + 255) & ~(uintptr_t)255; pp = r + bytes; return (void*)r;
  };
  int* deg  = (int*)alloc((size_t)N * 4);
  int* off  = (int*)alloc((size_t)(N + 1) * 4);
  int* pos  = (int*)alloc((size_t)N * 4);
  int* csr  = (int*)alloc((size_t)E * 4);
  int* bsum = (int*)alloc((size_t)NB * 4);
  int* bpre = (int*)alloc((size_t)NB * 4);
  ushort* xb  = (ushort*)alloc((size_t)N * 64 * 2);
  ushort* agg = (ushort*)alloc((size_t)N * 64 * 2);
  ushort* hb  = (ushort*)alloc((size_t)N * 64 * 2);
  ushort* zb  = (ushort*)alloc((size_t)N * 64 * 2);

  hipMemsetAsync(deg, 0, (size_t)N * 4, stream);
  cvt_k<<<(N * 32 + 255) / 256, 256, 0, stream>>>(x, xb, N * 32);
  hist_k<<<(E + 255) / 256, 256, 0, stream>>>(ei, deg, E);
  scan1_k<<<NB, 1024, 0, stream>>>(deg, off, bsum, N);
  scan2_k<<<1, 64, 0, stream>>>(bsum, bpre, off, NB, N);
  scan3_k<<<NB, 1024, 0, stream>>>(off, pos, bpre, N);
  fill_k<<<(E + 255) / 256, 256, 0, stream>>>(ei, pos, csr, E);
  // layer 0
  agg_k<<<2048, 256, 0, stream>>>(xb, off, csr, agg, N);
  node_k<<<512, 256, 0, stream>>>(agg, xb, wl0, wr0, b0, g0, lb0, hb, N);
  // layer 1
  agg_k<<<2048, 256, 0, stream>>>(hb, off, csr, agg, N);
  node_k<<<512, 256, 0, stream>>>(agg, hb, wl1, wr1, b1, g1, lb1, zb, N);
  // edge classifier
  edge_mfma_k<<<1024, 256, 0, stream>>>(ei, ea, zb, cw1, cb1, cw2, cb2, cw3, cb3, out, E);
}

// Round 4
// 561.228 us; speedup vs baseline: 3.4682x; 1.0417x over previous
//
#include <hip/hip_runtime.h>
#include <hip/hip_bf16.h>

#define N_NODES 100000
#define N_EDGES 1200000

typedef __attribute__((ext_vector_type(8))) short bfrag;
typedef __attribute__((ext_vector_type(4))) float ffrag;

union FragU { uint4 v; uint32_t u[4]; bfrag f; };

__device__ __forceinline__ ushort bfbits(float a) {
  union { __hip_bfloat16 h; ushort u; } c; c.h = __float2bfloat16(a); return c.u;
}
__device__ __forceinline__ uint32_t pkbf(float a, float b) {
  union { __hip_bfloat162 h; uint32_t u; } c;
  c.h = __float22bfloat162_rn(float2{a, b}); return c.u;
}
__device__ __forceinline__ uint32_t mul2bf(uint32_t a, uint32_t b) {
  union { uint32_t u; __hip_bfloat162 h; } x, y, r;
  x.u = a; y.u = b; r.h = __hmul2(x.h, y.h); return r.u;
}
__device__ __forceinline__ float bflo(uint32_t u) { return __int_as_float(u << 16); }
__device__ __forceinline__ float bfhi(uint32_t u) { return __int_as_float(u & 0xffff0000u); }

// ---------------- x -> bf16 ----------------

__global__ void cvt_k(const float* __restrict__ x, ushort* __restrict__ xb, int n2) {
  int i = blockIdx.x * blockDim.x + threadIdx.x;   // n2 = N*32 (pairs)
  if (i < n2) {
    float2 v = ((const float2*)x)[i];
    ((uint32_t*)xb)[i] = pkbf(v.x, v.y);
  }
}

// ---------------- CSR build ----------------

__global__ void hist_k(const int* __restrict__ ei, int* __restrict__ deg, int E) {
  int e = blockIdx.x * blockDim.x + threadIdx.x;
  if (e < E) atomicAdd(&deg[ei[E + e]], 1);
}

__global__ __launch_bounds__(1024) void scan1_k(const int* __restrict__ deg,
                                                int* __restrict__ off,
                                                int* __restrict__ bsum, int n) {
  __shared__ int wpart[16];
  __shared__ int wpre[16];
  int tid = threadIdx.x, lane = tid & 63, wid = tid >> 6;
  int i = blockIdx.x * 1024 + tid;
  int v = (i < n) ? deg[i] : 0;
  int x = v;
  #pragma unroll
  for (int o = 1; o < 64; o <<= 1) {
    int y = __shfl_up(x, o);
    if (lane >= o) x += y;
  }
  if (lane == 63) wpart[wid] = x;
  __syncthreads();
  if (tid == 0) {
    int run = 0;
    #pragma unroll
    for (int w = 0; w < 16; w++) { int t = wpart[w]; wpre[w] = run; run += t; }
    bsum[blockIdx.x] = run;
  }
  __syncthreads();
  if (i < n) off[i] = x - v + wpre[wid];
}

__global__ void scan2_k(const int* __restrict__ bsum, int* __restrict__ bpre,
                        int* __restrict__ off, int nb, int n) {
  if (threadIdx.x == 0) {
    int run = 0;
    for (int b = 0; b < nb; b++) { int t = bsum[b]; bpre[b] = run; run += t; }
    off[n] = run;
  }
}

__global__ __launch_bounds__(1024) void scan3_k(int* __restrict__ off, int* __restrict__ pos,
                                                const int* __restrict__ bpre, int n) {
  int i = blockIdx.x * 1024 + threadIdx.x;
  if (i < n) {
    int o = off[i] + bpre[blockIdx.x];
    off[i] = o;
    pos[i] = o;
  }
}

__global__ void fill_k(const int* __restrict__ ei, int* __restrict__ pos,
                       int* __restrict__ csr, int E) {
  int e = blockIdx.x * blockDim.x + threadIdx.x;
  if (e < E) {
    int d = ei[E + e];
    int p = atomicAdd(&pos[d], 1);
    csr[p] = ei[e];
  }
}

// ---------------- mean aggregation: 4 nodes/wave, 16 lanes x uint2 per row ----
// csr indices fetched as uniform broadcast loads per 16-lane group; 8 gathers
// in flight per node (32 per wave). No LDS -> full occupancy.

__global__ __launch_bounds__(256) void agg_k(
    const ushort* __restrict__ Xb, const int* __restrict__ off, const int* __restrict__ csr,
    ushort* __restrict__ aggout, int n) {
  int lane = threadIdx.x & 63;
  int quad = lane >> 4, f8 = lane & 15;
  int wave = blockIdx.x * 4 + (threadIdx.x >> 6);
  int nw = gridDim.x * 4;
  int nquads = (n + 3) >> 2;
  const uint2* X2 = (const uint2*)Xb;
  for (int p = wave; p < nquads; p += nw) {
    int i = p * 4 + quad;
    int ic = i < n ? i : n - 1;
    int s0 = off[ic], s1 = off[ic + 1];
    float a0 = 0.f, a1 = 0.f, a2 = 0.f, a3 = 0.f;
    for (int j = s0; j < s1; j += 8) {
      int id[8]; uint2 us[8];
      #pragma unroll
      for (int u = 0; u < 8; u++) {
        int jj = j + u;
        id[u] = csr[jj < s1 ? jj : s1 - 1];
      }
      #pragma unroll
      for (int u = 0; u < 8; u++) us[u] = X2[(size_t)id[u] * 16 + f8];
      #pragma unroll
      for (int u = 0; u < 8; u++) {
        if (j + u < s1) {
          a0 += bflo(us[u].x); a1 += bfhi(us[u].x);
          a2 += bflo(us[u].y); a3 += bfhi(us[u].y);
        }
      }
    }
    if (i < n) {
      float rdeg = 1.f / fmaxf((float)(s1 - s0), 1.f);
      uint2 w;
      w.x = pkbf(a0 * rdeg, a1 * rdeg);
      w.y = pkbf(a2 * rdeg, a3 * rdeg);
      ((uint2*)aggout)[(size_t)i * 16 + f8] = w;
    }
  }
}

// ---------------- node linear + LN + relu via MFMA ----------------

__global__ __launch_bounds__(256) void node_k(
    const ushort* __restrict__ agg, const ushort* __restrict__ selfb,
    const float* __restrict__ wl, const float* __restrict__ wr,
    const float* __restrict__ bias, const float* __restrict__ g, const float* __restrict__ lb,
    ushort* __restrict__ outb, int n) {
  __shared__ ushort wt[64 * 128];   // [n][k] swizzled, 16KB
  const int tid = threadIdx.x;
  for (int i = tid; i < 8192; i += 256) {
    int k = i >> 6, nn = i & 63;
    float v = (k < 64) ? wl[k * 64 + nn] : wr[(k - 64) * 64 + nn];
    wt[nn * 128 + (((k >> 3) ^ (nn & 7)) * 8) + (k & 7)] = bfbits(v);
  }
  __syncthreads();
  const int lane = tid & 63, wid = tid >> 6;
  const int ln = lane & 15, q = lane >> 4;
  float bias_n[4], g_n[4], lb_n[4];
  #pragma unroll
  for (int nt = 0; nt < 4; nt++) {
    bias_n[nt] = bias[nt * 16 + ln];
    g_n[nt] = g[nt * 16 + ln];
    lb_n[nt] = lb[nt * 16 + ln];
  }
  const int ntiles = (n + 15) >> 4;
  for (int t = blockIdx.x * 4 + wid; t < ntiles; t += gridDim.x * 4) {
    int node = t * 16 + ln;
    int nc = node < n ? node : n - 1;
    FragU afr[4];
    #pragma unroll
    for (int kk = 0; kk < 2; kk++) {
      afr[kk].v     = ((const uint4*)agg)[(size_t)nc * 8 + kk * 4 + q];
      afr[2 + kk].v = ((const uint4*)selfb)[(size_t)nc * 8 + kk * 4 + q];
    }
    ffrag acc[4];
    #pragma unroll
    for (int nt = 0; nt < 4; nt++) acc[nt] = ffrag{0.f, 0.f, 0.f, 0.f};
    #pragma unroll
    for (int kk = 0; kk < 4; kk++) {
      bfrag a = afr[kk].f;
      #pragma unroll
      for (int nt = 0; nt < 4; nt++) {
        int nn = nt * 16 + ln;
        int b = kk * 4 + q;
        const bfrag* bp = (const bfrag*)&wt[nn * 128 + ((b ^ (nn & 7)) * 8)];
        acc[nt] = __builtin_amdgcn_mfma_f32_16x16x32_bf16(a, *bp, acc[nt], 0, 0, 0);
      }
    }
    #pragma unroll
    for (int r = 0; r < 4; r++) {
      int m = t * 16 + q * 4 + r;
      float o[4];
      #pragma unroll
      for (int nt = 0; nt < 4; nt++) o[nt] = acc[nt][r] + bias_n[nt];
      float s = (o[0] + o[1]) + (o[2] + o[3]);
      #pragma unroll
      for (int mm = 1; mm < 16; mm <<= 1) s += __shfl_xor(s, mm);
      float mu = s * (1.f / 64.f);
      float v2 = 0.f;
      #pragma unroll
      for (int nt = 0; nt < 4; nt++) { float d2 = o[nt] - mu; v2 += d2 * d2; }
      #pragma unroll
      for (int mm = 1; mm < 16; mm <<= 1) v2 += __shfl_xor(v2, mm);
      float rs = rsqrtf(v2 * (1.f / 64.f) + 1e-5f);
      if (m < n) {
        #pragma unroll
        for (int nt = 0; nt < 4; nt++) {
          float y = fmaxf((o[nt] - mu) * rs * g_n[nt] + lb_n[nt], 0.f);
          outb[(size_t)m * 64 + nt * 16 + ln] = bfbits(y);
        }
      }
    }
  }
}

// ---------------- edge classifier: bf16 MFMA, W1/W2 fragments in registers ----
// Per wave: 16 edges. 28 L1 MFMAs + 4 L2 MFMAs; only LDS use is the per-wave
// 2KB h1 C-layout -> A-layout transpose tile. ~210 VGPR -> 2 waves/SIMD.

__global__ __launch_bounds__(256, 2) void edge_mfma_k(
    const int* __restrict__ ei, const float* __restrict__ ea,
    const ushort* __restrict__ zb,
    const float* __restrict__ cw1, const float* __restrict__ cb1,
    const float* __restrict__ cw2, const float* __restrict__ cb2,
    const float* __restrict__ cw3, const float* __restrict__ cb3,
    float* __restrict__ out, int E) {
  __shared__ ushort h1b[4][16 * 64];    // per-wave h1 tile, swizzled, 2KB each
  const int tid = threadIdx.x;
  const int lane = tid & 63, wid = tid >> 6;
  const int ln = lane & 15, q = lane >> 4;

  // W1^T B-fragments in registers: w1f[kk][tt]; n = tt*16+ln, k-block = kk*4+q
  FragU w1f[7][4];
  #pragma unroll
  for (int kk = 0; kk < 7; kk++) {
    #pragma unroll
    for (int tt = 0; tt < 4; tt++) {
      #pragma unroll
      for (int p = 0; p < 4; p++) {
        int k = (kk * 4 + q) * 8 + p * 2;
        int n = tt * 16 + ln;
        w1f[kk][tt].u[p] = pkbf(cw1[k * 64 + n], cw1[(k + 1) * 64 + n]);
      }
    }
  }
  // W2^T B-fragments: w2f[t2][kk]; k = kk*32 + q*8 + j, n = t2*16 + ln
  FragU w2f[2][2];
  #pragma unroll
  for (int t2 = 0; t2 < 2; t2++) {
    #pragma unroll
    for (int kk = 0; kk < 2; kk++) {
      #pragma unroll
      for (int p = 0; p < 4; p++) {
        int k = kk * 32 + q * 8 + p * 2;
        int n = t2 * 16 + ln;
        w2f[t2][kk].u[p] = pkbf(cw2[k * 32 + n], cw2[(k + 1) * 32 + n]);
      }
    }
  }

  float cb1v[4];
  #pragma unroll
  for (int t = 0; t < 4; t++) cb1v[t] = cb1[t * 16 + ln];
  float cb2a = cb2[ln], cb2b = cb2[16 + ln];
  float w3a = cw3[ln], w3b = cw3[16 + ln];
  float cb3v = cb3[0];

  ushort* hb = h1b[wid];
  const int ntiles = E >> 4;
  for (int t = blockIdx.x * 4 + wid; t < ntiles; t += gridDim.x * 4) {
    int e = t * 16 + ln;
    int s = ei[e], d = ei[E + e];

    FragU afr[7];
    #pragma unroll
    for (int kk = 0; kk < 2; kk++) {
      afr[kk].v     = ((const uint4*)zb)[(size_t)s * 8 + kk * 4 + q];
      afr[2 + kk].v = ((const uint4*)zb)[(size_t)d * 8 + kk * 4 + q];
    }
    {
      float4 lo = ((const float4*)ea)[(size_t)e * 8 + q * 2];
      float4 hi = ((const float4*)ea)[(size_t)e * 8 + q * 2 + 1];
      afr[6].u[0] = pkbf(lo.x, lo.y); afr[6].u[1] = pkbf(lo.z, lo.w);
      afr[6].u[2] = pkbf(hi.x, hi.y); afr[6].u[3] = pkbf(hi.z, hi.w);
    }
    #pragma unroll
    for (int kk = 0; kk < 2; kk++) {
      #pragma unroll
      for (int p = 0; p < 4; p++)
        afr[4 + kk].u[p] = mul2bf(afr[kk].u[p], afr[2 + kk].u[p]);
    }

    ffrag acc1[4];
    #pragma unroll
    for (int tt = 0; tt < 4; tt++) acc1[tt] = ffrag{0.f, 0.f, 0.f, 0.f};
    #pragma unroll
    for (int kk = 0; kk < 7; kk++) {
      bfrag a = afr[kk].f;
      #pragma unroll
      for (int tt = 0; tt < 4; tt++)
        acc1[tt] = __builtin_amdgcn_mfma_f32_16x16x32_bf16(a, w1f[kk][tt].f, acc1[tt], 0, 0, 0);
    }

    // h1 = relu(acc1 + cb1) -> swizzled LDS (C-layout -> A-layout transpose)
    #pragma unroll
    for (int tt = 0; tt < 4; tt++) {
      #pragma unroll
      for (int r = 0; r < 4; r++) {
        int m = q * 4 + r;
        int col = tt * 16 + ln;
        float v = fmaxf(acc1[tt][r] + cb1v[tt], 0.f);
        hb[m * 64 + (((col >> 3) ^ (m & 7)) * 8) + (col & 7)] = bfbits(v);
      }
    }

    ffrag acc2[2];
    acc2[0] = ffrag{0.f, 0.f, 0.f, 0.f};
    acc2[1] = ffrag{0.f, 0.f, 0.f, 0.f};
    #pragma unroll
    for (int kk = 0; kk < 2; kk++) {
      int b = kk * 4 + q;
      const bfrag* ap = (const bfrag*)&hb[ln * 64 + ((b ^ (ln & 7)) * 8)];
      bfrag a2 = *ap;
      acc2[0] = __builtin_amdgcn_mfma_f32_16x16x32_bf16(a2, w2f[0][kk].f, acc2[0], 0, 0, 0);
      acc2[1] = __builtin_amdgcn_mfma_f32_16x16x32_bf16(a2, w2f[1][kk].f, acc2[1], 0, 0, 0);
    }

    float p0, p1, p2, p3;
    {
      p0 = fmaxf(acc2[0][0] + cb2a, 0.f) * w3a + fmaxf(acc2[1][0] + cb2b, 0.f) * w3b;
      p1 = fmaxf(acc2[0][1] + cb2a, 0.f) * w3a + fmaxf(acc2[1][1] + cb2b, 0.f) * w3b;
      p2 = fmaxf(acc2[0][2] + cb2a, 0.f) * w3a + fmaxf(acc2[1][2] + cb2b, 0.f) * w3b;
      p3 = fmaxf(acc2[0][3] + cb2a, 0.f) * w3a + fmaxf(acc2[1][3] + cb2b, 0.f) * w3b;
    }
    #pragma unroll
    for (int o = 1; o < 16; o <<= 1) {
      p0 += __shfl_xor(p0, o);
      p1 += __shfl_xor(p1, o);
      p2 += __shfl_xor(p2, o);
      p3 += __shfl_xor(p3, o);
    }
    float keep = (ln == 0) ? p0 : (ln == 1) ? p1 : (ln == 2) ? p2 : p3;
    if (ln < 4) out[t * 16 + q * 4 + ln] = keep + cb3v;
  }
}

// ---------------- launch ----------------

extern "C" void kernel_launch(void* const* d_in, const int* in_sizes, int n_in,
                              void* d_out, int out_size, void* d_ws, size_t ws_size,
                              hipStream_t stream) {
  const float* x   = (const float*)d_in[0];
  const int*   ei  = (const int*)d_in[1];
  const float* ea  = (const float*)d_in[2];
  const float* wl0 = (const float*)d_in[3];
  const float* wr0 = (const float*)d_in[4];
  const float* b0  = (const float*)d_in[5];
  const float* g0  = (const float*)d_in[6];
  const float* lb0 = (const float*)d_in[7];
  const float* wl1 = (const float*)d_in[8];
  const float* wr1 = (const float*)d_in[9];
  const float* b1  = (const float*)d_in[10];
  const float* g1  = (const float*)d_in[11];
  const float* lb1 = (const float*)d_in[12];
  const float* cw1 = (const float*)d_in[13];
  const float* cb1 = (const float*)d_in[14];
  const float* cw2 = (const float*)d_in[15];
  const float* cb2 = (const float*)d_in[16];
  const float* cw3 = (const float*)d_in[17];
  const float* cb3 = (const float*)d_in[18];
  float* out = (float*)d_out;
  const int N = N_NODES, E = N_EDGES;
  const int NB = (N + 1023) / 1024;

  uintptr_t pp = (uintptr_t)d_ws;
  auto alloc = [&](size_t bytes) {
    uintptr_t r = (pp + 255) & ~(uintptr_t)255; pp = r + bytes; return (void*)r;
  };
  int* deg  = (int*)alloc((size_t)N * 4);
  int* off  = (int*)alloc((size_t)(N + 1) * 4);
  int* pos  = (int*)alloc((size_t)N * 4);
  int* csr  = (int*)alloc((size_t)E * 4);
  int* bsum = (int*)alloc((size_t)NB * 4);
  int* bpre = (int*)alloc((size_t)NB * 4);
  ushort* xb  = (ushort*)alloc((size_t)N * 64 * 2);
  ushort* agg = (ushort*)alloc((size_t)N * 64 * 2);
  ushort* hb  = (ushort*)alloc((size_t)N * 64 * 2);
  ushort* zb  = (ushort*)alloc((size_t)N * 64 * 2);

  hipMemsetAsync(deg, 0, (size_t)N * 4, stream);
  cvt_k<<<(N * 32 + 255) / 256, 256, 0, stream>>>(x, xb, N * 32);
  hist_k<<<(E + 255) / 256, 256, 0, stream>>>(ei, deg, E);
  scan1_k<<<NB, 1024, 0, stream>>>(deg, off, bsum, N);
  scan2_k<<<1, 64, 0, stream>>>(bsum, bpre, off, NB, N);
  scan3_k<<<NB, 1024, 0, stream>>>(off, pos, bpre, N);
  fill_k<<<(E + 255) / 256, 256, 0, stream>>>(ei, pos, csr, E);
  // layer 0
  agg_k<<<2048, 256, 0, stream>>>(xb, off, csr, agg, N);
  node_k<<<512, 256, 0, stream>>>(agg, xb, wl0, wr0, b0, g0, lb0, hb, N);
  // layer 1
  agg_k<<<2048, 256, 0, stream>>>(hb, off, csr, agg, N);
  node_k<<<512, 256, 0, stream>>>(agg, hb, wl1, wr1, b1, g1, lb1, zb, N);
  // edge classifier
  edge_mfma_k<<<512, 256, 0, stream>>>(ei, ea, zb, cw1, cb1, cw2, cb2, cw3, cb3, out, E);
}

// Round 5
// 515.071 us; speedup vs baseline: 3.7790x; 1.0896x over previous
//
#include <hip/hip_runtime.h>
#include <hip/hip_bf16.h>

#define N_NODES 100000
#define N_EDGES 1200000

typedef __attribute__((ext_vector_type(8))) short bfrag;
typedef __attribute__((ext_vector_type(4))) float ffrag;

union FragU { uint4 v; uint32_t u[4]; bfrag f; };

__device__ __forceinline__ ushort bfbits(float a) {
  union { __hip_bfloat16 h; ushort u; } c; c.h = __float2bfloat16(a); return c.u;
}
__device__ __forceinline__ uint32_t pkbf(float a, float b) {
  union { __hip_bfloat162 h; uint32_t u; } c;
  c.h = __float22bfloat162_rn(float2{a, b}); return c.u;
}
__device__ __forceinline__ uint32_t mul2bf(uint32_t a, uint32_t b) {
  union { uint32_t u; __hip_bfloat162 h; } x, y, r;
  x.u = a; y.u = b; r.h = __hmul2(x.h, y.h); return r.u;
}
__device__ __forceinline__ float bflo(uint32_t u) { return __int_as_float(u << 16); }
__device__ __forceinline__ float bfhi(uint32_t u) { return __int_as_float(u & 0xffff0000u); }

// ---------------- x -> bf16 ----------------

__global__ void cvt_k(const float* __restrict__ x, ushort* __restrict__ xb, int n2) {
  int i = blockIdx.x * blockDim.x + threadIdx.x;   // n2 = N*32 (pairs)
  if (i < n2) {
    float2 v = ((const float2*)x)[i];
    ((uint32_t*)xb)[i] = pkbf(v.x, v.y);
  }
}

// ---------------- CSR build ----------------
// hist also captures each edge's rank among same-dst edges (atomic return),
// so fill needs no second atomic pass.

__global__ void hist_k(const int* __restrict__ ei, int* __restrict__ deg,
                       int* __restrict__ rank, int E) {
  int e = blockIdx.x * blockDim.x + threadIdx.x;
  if (e < E) rank[e] = atomicAdd(&deg[ei[E + e]], 1);
}

__global__ __launch_bounds__(1024) void scan1_k(const int* __restrict__ deg,
                                                int* __restrict__ off,
                                                int* __restrict__ bsum, int n) {
  __shared__ int wpart[16];
  __shared__ int wpre[16];
  int tid = threadIdx.x, lane = tid & 63, wid = tid >> 6;
  int i = blockIdx.x * 1024 + tid;
  int v = (i < n) ? deg[i] : 0;
  int x = v;
  #pragma unroll
  for (int o = 1; o < 64; o <<= 1) {
    int y = __shfl_up(x, o);
    if (lane >= o) x += y;
  }
  if (lane == 63) wpart[wid] = x;
  __syncthreads();
  if (tid == 0) {
    int run = 0;
    #pragma unroll
    for (int w = 0; w < 16; w++) { int t = wpart[w]; wpre[w] = run; run += t; }
    bsum[blockIdx.x] = run;
  }
  __syncthreads();
  if (i < n) off[i] = x - v + wpre[wid];
}

__global__ void scan2_k(const int* __restrict__ bsum, int* __restrict__ bpre,
                        int* __restrict__ off, int nb, int n) {
  if (threadIdx.x == 0) {
    int run = 0;
    for (int b = 0; b < nb; b++) { int t = bsum[b]; bpre[b] = run; run += t; }
    off[n] = run;
  }
}

__global__ __launch_bounds__(1024) void scan3_k(int* __restrict__ off,
                                                const int* __restrict__ bpre, int n) {
  int i = blockIdx.x * 1024 + threadIdx.x;
  if (i < n) off[i] += bpre[blockIdx.x];
}

__global__ void fill_k(const int* __restrict__ ei, const int* __restrict__ off,
                       const int* __restrict__ rank, int* __restrict__ csr, int E) {
  int e = blockIdx.x * blockDim.x + threadIdx.x;
  if (e < E) {
    int d = ei[E + e];
    int p = off[d] + rank[e];
    __builtin_nontemporal_store(ei[e], &csr[p]);
  }
}

// ---------------- mean aggregation: 4 nodes/wave, 16 lanes x uint2 per row ----

__global__ __launch_bounds__(256) void agg_k(
    const ushort* __restrict__ Xb, const int* __restrict__ off, const int* __restrict__ csr,
    ushort* __restrict__ aggout, int n) {
  int lane = threadIdx.x & 63;
  int quad = lane >> 4, f8 = lane & 15;
  int wave = blockIdx.x * 4 + (threadIdx.x >> 6);
  int nw = gridDim.x * 4;
  int nquads = (n + 3) >> 2;
  const uint2* X2 = (const uint2*)Xb;
  for (int p = wave; p < nquads; p += nw) {
    int i = p * 4 + quad;
    int ic = i < n ? i : n - 1;
    int s0 = off[ic], s1 = off[ic + 1];
    float a0 = 0.f, a1 = 0.f, a2 = 0.f, a3 = 0.f;
    for (int j = s0; j < s1; j += 8) {
      int id[8]; uint2 us[8];
      #pragma unroll
      for (int u = 0; u < 8; u++) {
        int jj = j + u;
        id[u] = csr[jj < s1 ? jj : s1 - 1];
      }
      #pragma unroll
      for (int u = 0; u < 8; u++) us[u] = X2[(size_t)id[u] * 16 + f8];
      #pragma unroll
      for (int u = 0; u < 8; u++) {
        if (j + u < s1) {
          a0 += bflo(us[u].x); a1 += bfhi(us[u].x);
          a2 += bflo(us[u].y); a3 += bfhi(us[u].y);
        }
      }
    }
    if (i < n) {
      float rdeg = 1.f / fmaxf((float)(s1 - s0), 1.f);
      uint2 w;
      w.x = pkbf(a0 * rdeg, a1 * rdeg);
      w.y = pkbf(a2 * rdeg, a3 * rdeg);
      ((uint2*)aggout)[(size_t)i * 16 + f8] = w;
    }
  }
}

// ---------------- node linear + LN + relu via MFMA ----------------

__global__ __launch_bounds__(256) void node_k(
    const ushort* __restrict__ agg, const ushort* __restrict__ selfb,
    const float* __restrict__ wl, const float* __restrict__ wr,
    const float* __restrict__ bias, const float* __restrict__ g, const float* __restrict__ lb,
    ushort* __restrict__ outb, int n) {
  __shared__ ushort wt[64 * 128];   // [n][k] swizzled, 16KB
  const int tid = threadIdx.x;
  for (int i = tid; i < 8192; i += 256) {
    int k = i >> 6, nn = i & 63;
    float v = (k < 64) ? wl[k * 64 + nn] : wr[(k - 64) * 64 + nn];
    wt[nn * 128 + (((k >> 3) ^ (nn & 7)) * 8) + (k & 7)] = bfbits(v);
  }
  __syncthreads();
  const int lane = tid & 63, wid = tid >> 6;
  const int ln = lane & 15, q = lane >> 4;
  float bias_n[4], g_n[4], lb_n[4];
  #pragma unroll
  for (int nt = 0; nt < 4; nt++) {
    bias_n[nt] = bias[nt * 16 + ln];
    g_n[nt] = g[nt * 16 + ln];
    lb_n[nt] = lb[nt * 16 + ln];
  }
  const int ntiles = (n + 15) >> 4;
  for (int t = blockIdx.x * 4 + wid; t < ntiles; t += gridDim.x * 4) {
    int node = t * 16 + ln;
    int nc = node < n ? node : n - 1;
    FragU afr[4];
    #pragma unroll
    for (int kk = 0; kk < 2; kk++) {
      afr[kk].v     = ((const uint4*)agg)[(size_t)nc * 8 + kk * 4 + q];
      afr[2 + kk].v = ((const uint4*)selfb)[(size_t)nc * 8 + kk * 4 + q];
    }
    ffrag acc[4];
    #pragma unroll
    for (int nt = 0; nt < 4; nt++) acc[nt] = ffrag{0.f, 0.f, 0.f, 0.f};
    #pragma unroll
    for (int kk = 0; kk < 4; kk++) {
      bfrag a = afr[kk].f;
      #pragma unroll
      for (int nt = 0; nt < 4; nt++) {
        int nn = nt * 16 + ln;
        int b = kk * 4 + q;
        const bfrag* bp = (const bfrag*)&wt[nn * 128 + ((b ^ (nn & 7)) * 8)];
        acc[nt] = __builtin_amdgcn_mfma_f32_16x16x32_bf16(a, *bp, acc[nt], 0, 0, 0);
      }
    }
    #pragma unroll
    for (int r = 0; r < 4; r++) {
      int m = t * 16 + q * 4 + r;
      float o[4];
      #pragma unroll
      for (int nt = 0; nt < 4; nt++) o[nt] = acc[nt][r] + bias_n[nt];
      float s = (o[0] + o[1]) + (o[2] + o[3]);
      #pragma unroll
      for (int mm = 1; mm < 16; mm <<= 1) s += __shfl_xor(s, mm);
      float mu = s * (1.f / 64.f);
      float v2 = 0.f;
      #pragma unroll
      for (int nt = 0; nt < 4; nt++) { float d2 = o[nt] - mu; v2 += d2 * d2; }
      #pragma unroll
      for (int mm = 1; mm < 16; mm <<= 1) v2 += __shfl_xor(v2, mm);
      float rs = rsqrtf(v2 * (1.f / 64.f) + 1e-5f);
      if (m < n) {
        #pragma unroll
        for (int nt = 0; nt < 4; nt++) {
          float y = fmaxf((o[nt] - mu) * rs * g_n[nt] + lb_n[nt], 0.f);
          outb[(size_t)m * 64 + nt * 16 + ln] = bfbits(y);
        }
      }
    }
  }
}

// ---------------- edge classifier: bf16 MFMA, W1 in LDS, 1-tile prefetch ----
// Per wave: 16 edges. Next tile's ei/z/ea gathers issue before current tile's
// 32 MFMAs + h1 LDS transpose, overlapping the L3 gather round-trip.

__global__ __launch_bounds__(256) void edge_mfma_k(
    const int* __restrict__ ei, const float* __restrict__ ea,
    const ushort* __restrict__ zb,
    const float* __restrict__ cw1, const float* __restrict__ cb1,
    const float* __restrict__ cw2, const float* __restrict__ cb2,
    const float* __restrict__ cw3, const float* __restrict__ cb3,
    float* __restrict__ out, int E) {
  __shared__ ushort wt1[64 * 256];      // W1^T [n][k], XOR-swizzled, 32KB
  __shared__ ushort h1b[4][16 * 64];    // per-wave h1 tile, swizzled, 2KB each
  const int tid = threadIdx.x;

  for (int i = tid; i < 224 * 64; i += 256) {
    int k = i >> 6, n = i & 63;
    int blk = k >> 3;
    wt1[n * 256 + ((blk ^ (n & 7)) * 8) + (k & 7)] = bfbits(cw1[i]);
  }
  __syncthreads();

  const int lane = tid & 63, wid = tid >> 6;
  const int ln = lane & 15, q = lane >> 4;

  float cb1v[4];
  #pragma unroll
  for (int t = 0; t < 4; t++) cb1v[t] = cb1[t * 16 + ln];
  float cb2a = cb2[ln], cb2b = cb2[16 + ln];
  float w3a = cw3[ln], w3b = cw3[16 + ln];
  float cb3v = cb3[0];

  // W2^T B-fragments in registers (16 dwords)
  FragU w2f[2][2];
  #pragma unroll
  for (int t2 = 0; t2 < 2; t2++) {
    #pragma unroll
    for (int kk = 0; kk < 2; kk++) {
      #pragma unroll
      for (int p = 0; p < 4; p++) {
        int k = kk * 32 + q * 8 + p * 2;
        int n = t2 * 16 + ln;
        w2f[t2][kk].u[p] = pkbf(cw2[k * 32 + n], cw2[(k + 1) * 32 + n]);
      }
    }
  }

  ushort* hb = h1b[wid];
  const int ntiles = E >> 4;
  const int stride = gridDim.x * 4;
  int t = blockIdx.x * 4 + wid;

  // prologue: issue gathers for first tile
  FragU curz[4]; float4 ceal, ceah;
  if (t < ntiles) {
    int e = t * 16 + ln;
    int s = ei[e], d = ei[E + e];
    curz[0].v = ((const uint4*)zb)[(size_t)s * 8 + q];
    curz[1].v = ((const uint4*)zb)[(size_t)s * 8 + 4 + q];
    curz[2].v = ((const uint4*)zb)[(size_t)d * 8 + q];
    curz[3].v = ((const uint4*)zb)[(size_t)d * 8 + 4 + q];
    ceal = ((const float4*)ea)[(size_t)e * 8 + q * 2];
    ceah = ((const float4*)ea)[(size_t)e * 8 + q * 2 + 1];
  }

  for (; t < ntiles; t += stride) {
    int tn = t + stride;
    FragU nz[4]; float4 neal, neah;
    if (tn < ntiles) {
      int e2 = tn * 16 + ln;
      int s2 = ei[e2], d2 = ei[E + e2];
      nz[0].v = ((const uint4*)zb)[(size_t)s2 * 8 + q];
      nz[1].v = ((const uint4*)zb)[(size_t)s2 * 8 + 4 + q];
      nz[2].v = ((const uint4*)zb)[(size_t)d2 * 8 + q];
      nz[3].v = ((const uint4*)zb)[(size_t)d2 * 8 + 4 + q];
      neal = ((const float4*)ea)[(size_t)e2 * 8 + q * 2];
      neah = ((const float4*)ea)[(size_t)e2 * 8 + q * 2 + 1];
    }

    FragU afr[7];
    afr[0] = curz[0]; afr[1] = curz[1]; afr[2] = curz[2]; afr[3] = curz[3];
    #pragma unroll
    for (int kk = 0; kk < 2; kk++) {
      #pragma unroll
      for (int p = 0; p < 4; p++)
        afr[4 + kk].u[p] = mul2bf(curz[kk].u[p], curz[2 + kk].u[p]);
    }
    afr[6].u[0] = pkbf(ceal.x, ceal.y); afr[6].u[1] = pkbf(ceal.z, ceal.w);
    afr[6].u[2] = pkbf(ceah.x, ceah.y); afr[6].u[3] = pkbf(ceah.z, ceah.w);

    ffrag acc1[4];
    #pragma unroll
    for (int tt = 0; tt < 4; tt++) acc1[tt] = ffrag{0.f, 0.f, 0.f, 0.f};
    #pragma unroll
    for (int kk = 0; kk < 7; kk++) {
      bfrag a = afr[kk].f;
      #pragma unroll
      for (int tt = 0; tt < 4; tt++) {
        int n = tt * 16 + ln;
        int b = kk * 4 + q;
        const bfrag* bp = (const bfrag*)&wt1[n * 256 + ((b ^ (n & 7)) * 8)];
        acc1[tt] = __builtin_amdgcn_mfma_f32_16x16x32_bf16(a, *bp, acc1[tt], 0, 0, 0);
      }
    }

    // h1 = relu(acc1 + cb1) -> swizzled LDS (C-layout -> A-layout transpose)
    #pragma unroll
    for (int tt = 0; tt < 4; tt++) {
      #pragma unroll
      for (int r = 0; r < 4; r++) {
        int m = q * 4 + r;
        int col = tt * 16 + ln;
        float v = fmaxf(acc1[tt][r] + cb1v[tt], 0.f);
        hb[m * 64 + (((col >> 3) ^ (m & 7)) * 8) + (col & 7)] = bfbits(v);
      }
    }

    ffrag acc2[2];
    acc2[0] = ffrag{0.f, 0.f, 0.f, 0.f};
    acc2[1] = ffrag{0.f, 0.f, 0.f, 0.f};
    #pragma unroll
    for (int kk = 0; kk < 2; kk++) {
      int b = kk * 4 + q;
      const bfrag* ap = (const bfrag*)&hb[ln * 64 + ((b ^ (ln & 7)) * 8)];
      bfrag a2 = *ap;
      acc2[0] = __builtin_amdgcn_mfma_f32_16x16x32_bf16(a2, w2f[0][kk].f, acc2[0], 0, 0, 0);
      acc2[1] = __builtin_amdgcn_mfma_f32_16x16x32_bf16(a2, w2f[1][kk].f, acc2[1], 0, 0, 0);
    }

    float p0, p1, p2, p3;
    {
      p0 = fmaxf(acc2[0][0] + cb2a, 0.f) * w3a + fmaxf(acc2[1][0] + cb2b, 0.f) * w3b;
      p1 = fmaxf(acc2[0][1] + cb2a, 0.f) * w3a + fmaxf(acc2[1][1] + cb2b, 0.f) * w3b;
      p2 = fmaxf(acc2[0][2] + cb2a, 0.f) * w3a + fmaxf(acc2[1][2] + cb2b, 0.f) * w3b;
      p3 = fmaxf(acc2[0][3] + cb2a, 0.f) * w3a + fmaxf(acc2[1][3] + cb2b, 0.f) * w3b;
    }
    #pragma unroll
    for (int o = 1; o < 16; o <<= 1) {
      p0 += __shfl_xor(p0, o);
      p1 += __shfl_xor(p1, o);
      p2 += __shfl_xor(p2, o);
      p3 += __shfl_xor(p3, o);
    }
    float keep = (ln == 0) ? p0 : (ln == 1) ? p1 : (ln == 2) ? p2 : p3;
    if (ln < 4) out[t * 16 + q * 4 + ln] = keep + cb3v;

    curz[0] = nz[0]; curz[1] = nz[1]; curz[2] = nz[2]; curz[3] = nz[3];
    ceal = neal; ceah = neah;
  }
}

// ---------------- launch ----------------

extern "C" void kernel_launch(void* const* d_in, const int* in_sizes, int n_in,
                              void* d_out, int out_size, void* d_ws, size_t ws_size,
                              hipStream_t stream) {
  const float* x   = (const float*)d_in[0];
  const int*   ei  = (const int*)d_in[1];
  const float* ea  = (const float*)d_in[2];
  const float* wl0 = (const float*)d_in[3];
  const float* wr0 = (const float*)d_in[4];
  const float* b0  = (const float*)d_in[5];
  const float* g0  = (const float*)d_in[6];
  const float* lb0 = (const float*)d_in[7];
  const float* wl1 = (const float*)d_in[8];
  const float* wr1 = (const float*)d_in[9];
  const float* b1  = (const float*)d_in[10];
  const float* g1  = (const float*)d_in[11];
  const float* lb1 = (const float*)d_in[12];
  const float* cw1 = (const float*)d_in[13];
  const float* cb1 = (const float*)d_in[14];
  const float* cw2 = (const float*)d_in[15];
  const float* cb2 = (const float*)d_in[16];
  const float* cw3 = (const float*)d_in[17];
  const float* cb3 = (const float*)d_in[18];
  float* out = (float*)d_out;
  const int N = N_NODES, E = N_EDGES;
  const int NB = (N + 1023) / 1024;

  uintptr_t pp = (uintptr_t)d_ws;
  auto alloc = [&](size_t bytes) {
    uintptr_t r = (pp + 255) & ~(uintptr_t)255; pp = r + bytes; return (void*)r;
  };
  int* deg  = (int*)alloc((size_t)N * 4);
  int* off  = (int*)alloc((size_t)(N + 1) * 4);
  int* rank = (int*)alloc((size_t)E * 4);
  int* csr  = (int*)alloc((size_t)E * 4);
  int* bsum = (int*)alloc((size_t)NB * 4);
  int* bpre = (int*)alloc((size_t)NB * 4);
  ushort* xb  = (ushort*)alloc((size_t)N * 64 * 2);
  ushort* agg = (ushort*)alloc((size_t)N * 64 * 2);
  ushort* hb  = (ushort*)alloc((size_t)N * 64 * 2);
  ushort* zb  = (ushort*)alloc((size_t)N * 64 * 2);

  hipMemsetAsync(deg, 0, (size_t)N * 4, stream);
  cvt_k<<<(N * 32 + 255) / 256, 256, 0, stream>>>(x, xb, N * 32);
  hist_k<<<(E + 255) / 256, 256, 0, stream>>>(ei, deg, rank, E);
  scan1_k<<<NB, 1024, 0, stream>>>(deg, off, bsum, N);
  scan2_k<<<1, 64, 0, stream>>>(bsum, bpre, off, NB, N);
  scan3_k<<<NB, 1024, 0, stream>>>(off, bpre, N);
  fill_k<<<(E + 255) / 256, 256, 0, stream>>>(ei, off, rank, csr, E);
  // layer 0
  agg_k<<<2048, 256, 0, stream>>>(xb, off, csr, agg, N);
  node_k<<<512, 256, 0, stream>>>(agg, xb, wl0, wr0, b0, g0, lb0, hb, N);
  // layer 1
  agg_k<<<2048, 256, 0, stream>>>(hb, off, csr, agg, N);
  node_k<<<512, 256, 0, stream>>>(agg, hb, wl1, wr1, b1, g1, lb1, zb, N);
  // edge classifier
  edge_mfma_k<<<1024, 256, 0, stream>>>(ei, ea, zb, cw1, cb1, cw2, cb2, cw3, cb3, out, E);
}